// Round 11
// baseline (16695.062 us; speedup 1.0000x reference)
//
#include <hip/hip_runtime.h>

// ---------------------------------------------------------------------------
// 3-layer LayerNorm-GRU (haste style), B=32 T=512 IN=128 H=1024 OUT=80
// Round 17: R15 base (proven 3357us/layer) + data-as-flag tagged stats.
//   R16 post-mortem: rotating virgin buffers neutral -> LLC bandwidth was
//   NOT the cost; the serialized RTT chain is. The stats hop's
//   ack->RMW->poll (~1.1us/step) is deleted by embedding the step tag in
//   the SAME 16B store as the data: entry = (s, tag, q, tag), each 8B half
//   self-validating (8B store atomicity is HW-guaranteed). Consumers gather
//   16 tagged quads with in-flight bypass loads and retry stale tags.
//   - cntA counter, its vmcnt-ack, RMW add, poll, and barrier: GONE.
//   - 4 barriers/step (was 5).
//   - WAR safe: block writes stats(t+1) only after cntB poll(t+1), which
//     requires every wave's gather(t) done (gates depend on it).
//   - tags monotonic across layers (abase+t+1), never reused; memset tag=0.
//   h hop unchanged from R15: block-major hglob, sc1 publish -> wave
//   vmcnt(0) -> sharded cntB add; tid<32 poll; bypass af loads.
// ---------------------------------------------------------------------------

typedef float    f32x4 __attribute__((ext_vector_type(4)));
typedef _Float16 f16x8 __attribute__((ext_vector_type(8)));

#define HH      1024
#define TT      512
#define BBATCH  32
#define H3      3072
#define MROWS   16384      // B*T
#define NBLK_R  128        // compute blocks
#define HPB     8          // h-indices per recurrence block
#define COLS    24         // 3*HPB columns of R per block
#define LN_EPS  1e-5f

// workspace layout (bytes)
#define OFF_CTRL   0u                 // cntB 32 lines = 4 KB
#define OFF_PST    4096u              // tagged stats [128][32][16B] = 64 KB
#define OFF_H      69632u             // h fp16 block-major [128][32][8] = 64 KB
#define OFF_HF     135168u            // h fp32 [32][1024] = 128 KB (ends 266240)
#define CTRL_BYTES 266240u            // memset region
#define OFF_WLB    327680u            // Wlin^T fp16 [80][1024]  = 160 KB
#define OFF_WB     524288u            // W^T fp16 [3072][K<=1024] = 6 MB
#define OFF_XBF    (8ull<<20)         // x fp16 [16384][128]     = 4 MB
#define OFF_WX     (16ull<<20)        // wx fp16 [16384][3072]   = 96 MB
#define OFF_HSA    (112ull<<20)       // hs fp16 [16384][1024]   = 32 MB
#define OFF_HSB    (144ull<<20)       // hs fp16 [16384][1024]   = 32 MB  (end 176 MB)

#define ALOAD(p)    __hip_atomic_load((p),  __ATOMIC_RELAXED, __HIP_MEMORY_SCOPE_AGENT)
#define ASTORE(p,v) __hip_atomic_store((p), (v), __ATOMIC_RELAXED, __HIP_MEMORY_SCOPE_AGENT)
#define AADD(p)     __hip_atomic_fetch_add((p), 1u, __ATOMIC_RELAXED, __HIP_MEMORY_SCOPE_AGENT)

// LLC-coherent 16B ops (bypass L1 via sc0, L2 via sc1)
__device__ __forceinline__ f16x8 ldg_h16(const _Float16* p) {
  f16x8 r;
  asm volatile("global_load_dwordx4 %0, %1, off sc0 sc1" : "=v"(r) : "v"(p));
  return r;
}
__device__ __forceinline__ f32x4 ldg_f32x4(const float* p) {
  f32x4 r;
  asm volatile("global_load_dwordx4 %0, %1, off sc0 sc1" : "=v"(r) : "v"(p));
  return r;
}
__device__ __forceinline__ void stg_f32x4(float* p, f32x4 v) {
  asm volatile("global_store_dwordx4 %0, %1, off sc0 sc1" :: "v"(p), "v"(v) : "memory");
}

__device__ __forceinline__ float sigf(float x) {
  return __builtin_amdgcn_rcpf(1.f + __expf(-x));
}
__device__ __forceinline__ float tanhfast(float x) {
  const float e2 = __expf(2.f * x);
  return 1.f - 2.f * __builtin_amdgcn_rcpf(e2 + 1.f);
}

// ---------------------------------------------------------------------------
// init: x fp32 -> fp16 ; Wlin [1024][80] -> Wlb^T fp16 [80][1024]
__global__ __launch_bounds__(256, 1) void k_init(
    const float* __restrict__ x, _Float16* __restrict__ xb,
    const float* __restrict__ Wlin, _Float16* __restrict__ Wlb)
{
  const size_t stride = (size_t)gridDim.x * 256;
  for (size_t i = (size_t)blockIdx.x * 256 + threadIdx.x; i < (size_t)MROWS * 128; i += stride)
    xb[i] = (_Float16)x[i];
  for (size_t i = (size_t)blockIdx.x * 256 + threadIdx.x; i < 80u * 1024u; i += stride) {
    const size_t n = i >> 10, k = i & 1023u;
    Wlb[i] = (_Float16)Wlin[k * 80 + n];
  }
}

// W fp32 [K][3072] -> Wb fp16 [3072][K] (n-major for B-fragments)
__global__ __launch_bounds__(256, 1) void k_convW(
    const float* __restrict__ W, _Float16* __restrict__ Wb, const int K)
{
  const int n = blockIdx.x;
  for (int k = threadIdx.x; k < K; k += 256)
    Wb[(size_t)n * K + k] = (_Float16)W[(size_t)k * H3 + n];
}

// Cw[16384][3072] (fp16, raw pre-LN) = A[16384][K] @ W[K][3072]
__global__ __launch_bounds__(256, 1) void k_gemm(
    const _Float16* __restrict__ A,
    const _Float16* __restrict__ Bw,   // [3072][K]
    _Float16* __restrict__ Cw,
    const int K)
{
  __shared__ _Float16 Bs[64][40];
  const int tid = threadIdx.x;
  const int lane = tid & 63, wv = tid >> 6;
  const int l15 = lane & 15, quad = lane >> 4;
  const int tilem = blockIdx.x / 48, tilen = blockIdx.x % 48;
  const int mbase = tilem * 64 + wv * 16;
  const size_t nbase = (size_t)tilen * 64;
  f32x4 acc[4] = {{0.f,0.f,0.f,0.f},{0.f,0.f,0.f,0.f},{0.f,0.f,0.f,0.f},{0.f,0.f,0.f,0.f}};
  const _Float16* arow = A + (size_t)(mbase + l15) * K + quad * 8;
  const int sn = tid >> 2, sk = (tid & 3) * 8;
  const _Float16* bsrc = Bw + (nbase + sn) * K + sk;
  for (int kc = 0; kc < K; kc += 32) {
    __syncthreads();
    *(f16x8*)(&Bs[sn][sk]) = *(const f16x8*)(bsrc + kc);
    __syncthreads();
    const f16x8 af = *(const f16x8*)(arow + kc);
#pragma unroll
    for (int nt = 0; nt < 4; ++nt) {
      const f16x8 bv = *(const f16x8*)(&Bs[nt * 16 + l15][quad * 8]);
      acc[nt] = __builtin_amdgcn_mfma_f32_16x16x32_f16(af, bv, acc[nt], 0, 0, 0);
    }
  }
#pragma unroll
  for (int nt = 0; nt < 4; ++nt)
#pragma unroll
    for (int j = 0; j < 4; ++j)
      Cw[(size_t)(mbase + quad * 4 + j) * H3 + nbase + nt * 16 + l15] = (_Float16)acc[nt][j];
}

// in-place LayerNorm * gw over rows of wx (3072 cols), one row per wave
__global__ __launch_bounds__(256, 1) void k_ln(
    _Float16* __restrict__ wxp, const float* __restrict__ gw)
{
  const int wv = threadIdx.x >> 6, lane = threadIdx.x & 63;
  const size_t row = (size_t)blockIdx.x * 4 + wv;
  _Float16* p = wxp + row * H3 + lane * 8;
  float vals[48];
  float s = 0.f, q = 0.f;
#pragma unroll
  for (int c = 0; c < 6; ++c) {
    const f16x8 v = *(const f16x8*)(p + c * 512);
#pragma unroll
    for (int j = 0; j < 8; ++j) {
      const float f = (float)v[j];
      vals[c * 8 + j] = f; s += f; q += f * f;
    }
  }
#pragma unroll
  for (int m = 1; m < 64; m <<= 1) { s += __shfl_xor(s, m); q += __shfl_xor(q, m); }
  const float mean = s * (1.f / H3);
  const float var  = q * (1.f / H3) - mean * mean;
  const float inv  = rsqrtf(var + LN_EPS);
#pragma unroll
  for (int c = 0; c < 6; ++c) {
    f16x8 o;
#pragma unroll
    for (int j = 0; j < 8; ++j)
      o[j] = (_Float16)((vals[c * 8 + j] - mean) * inv * gw[c * 512 + lane * 8 + j]);
    *(f16x8*)(p + c * 512) = o;
  }
}

// ---------------------------------------------------------------------------
// recurrence: 512 steps, 128 blocks, tagged-stats exchange, 4 barriers/step
__global__ __launch_bounds__(256, 1) void k_recur(
    const float* __restrict__ R, const float* __restrict__ bx,
    const float* __restrict__ br, const float* __restrict__ gr,
    const _Float16* __restrict__ wx,
    _Float16* __restrict__ hs_out,
    unsigned* __restrict__ hglob,     // h fp16 block-major [128][32][8] as u32
    float* __restrict__ hf32,
    float* __restrict__ pst,          // tagged stats [128][32] x (s,tag,q,tag)
    unsigned* __restrict__ ctrl,
    const unsigned abase,             // l*TT
    const unsigned hbase)             // l*(TT+1)
{
  const int tid = threadIdx.x;
  const int blk = blockIdx.x;
  unsigned* cntB = ctrl;              // 32 lines, word stride 32 (16 adds/line)

  __shared__ _Float16 Rs[COLS][HH + 8];
  __shared__ float rhp[2][BBATCH][27];    // K-half partials (odd stride)
  __shared__ float statb[BBATCH][2];
  __shared__ float predS[8][33];
  __shared__ float predQ[8][33];

  const int lane = tid & 63;
  const int wv   = tid >> 6;
  const int mh   = wv >> 1;       // which 16 batch rows
  const int kh   = wv & 1;        // which K half (512)
  const int l15  = lane & 15;
  const int quad = lane >> 4;
  const int kb   = kh * 512;
  const int lineB = ((blk & 7) * 4 + wv) * 32;   // cntB shard for this wave

  // load R slice (cols {i, H+i, 2H+i} for i in [blk*8, blk*8+8)), fp32->fp16
  for (int n = 0; n < COLS; ++n) {
    const int gc = (n >> 3) * HH + blk * HPB + (n & 7);
    for (int k = tid; k < HH; k += 256)
      Rs[n][k] = (_Float16)R[(size_t)k * H3 + gc];
  }

  // per-thread gate ownership: (batch row, h-index)
  const int b_row = tid >> 3;
  const int jj    = tid & 7;
  const int gi    = blk * HPB + jj;
  const float bxz = bx[gi], bxr = bx[HH + gi], bxg = bx[2 * HH + gi];
  const float brz = br[gi], brr = br[HH + gi], brg = br[2 * HH + gi];
  const float grz = gr[gi], grr = gr[HH + gi], grg = gr[2 * HH + gi];
  float hloc = hf32[b_row * HH + gi];

  // initial coherent publish of own h slice (block-major, sc1 u32 pairs)
  {
    union { _Float16 f; unsigned short s; } hc; hc.f = (_Float16)hloc;
    const unsigned short mybits = hc.s;
    const unsigned short pbits  = (unsigned short)__shfl_xor((int)mybits, 1);
    if ((jj & 1) == 0) {
      const unsigned w = (unsigned)mybits | ((unsigned)pbits << 16);
      ASTORE(&hglob[blk * 128 + b_row * 4 + (jj >> 1)], w);
    }
  }
  asm volatile("s_waitcnt vmcnt(0)" ::: "memory");   // wave-local drain
  if (lane == 0) AADD(&cntB[lineB]);

  // consumer base: block-major chunk (kh*64 + quad), row (mh*16 + l15)
  const _Float16* hread = (const _Float16*)hglob;
  const _Float16* hrow  = hread + (size_t)(kh * 64 + quad) * 256
                                + (size_t)(mh * 16 + l15) * 8;
  const int n1 = 16 + (l15 & 7);          // ntile1 row (lanes >=8 read dup, masked)
  // stats gather assignment: block-group (tid>>5), row (tid&31)
  const int grp = tid >> 5;
  const int rr  = tid & 31;
  const float* gbase = pst + ((size_t)(grp * 16) * 32 + rr) * 4;

  for (int t = 0; t < TT; ++t) {
    const float tagf = (float)(abase + (unsigned)t + 1u);
    // prefetch phase-2 wx operands (t-only dependence; L2-resident)
    const _Float16* wrow = wx + (size_t)(b_row * TT + t) * H3;
    const float wz = (float)wrow[gi];
    const float wr = (float)wrow[HH + gi];
    const float wg = (float)wrow[2 * HH + gi];

    // ---- wait for all 512 wave h-publishes (32 sharded lines, tight poll)
    if (tid < 32) {
      const unsigned* p = cntB + tid * 32;
      const unsigned tgt = 16u * (hbase + (unsigned)t + 1u);
      int spins = 0;
      while (ALOAD(p) < tgt) { if (++spins > (1 << 24)) break; }
    }
    __syncthreads();                                   // barrier 1

    // ---- phase 1: 16 LLC-coherent A loads fully in flight, then MFMA
    f16x8 af[16];
#pragma unroll
    for (int ks = 0; ks < 16; ++ks)
      af[ks] = ldg_h16(hrow + ks * 1024);              // +4 blocks per ks
    asm volatile("s_waitcnt vmcnt(0)" ::: "memory");
    f32x4 acc0 = {0.f,0.f,0.f,0.f}, acc1 = {0.f,0.f,0.f,0.f};
#pragma unroll
    for (int ks = 0; ks < 16; ++ks) {
      const f16x8 b0 = *(const f16x8*)(&Rs[l15][kb + ks * 32 + quad * 8]);
      acc0 = __builtin_amdgcn_mfma_f32_16x16x32_f16(af[ks], b0, acc0, 0, 0, 0);
      const f16x8 b1 = *(const f16x8*)(&Rs[n1][kb + ks * 32 + quad * 8]);
      acc1 = __builtin_amdgcn_mfma_f32_16x16x32_f16(af[ks], b1, acc1, 0, 0, 0);
    }
    // write K-half partials (C layout: row=quad*4+j, col=l15)
#pragma unroll
    for (int j = 0; j < 4; ++j) {
      rhp[kh][mh * 16 + quad * 4 + j][l15] = acc0[j];
      if (l15 < 8) rhp[kh][mh * 16 + quad * 4 + j][16 + l15] = acc1[j];
    }
    __syncthreads();                                   // barrier 2

    // ---- combine K halves; per-row LN partial stats (8-thread shfl reduce)
    const float rz = rhp[0][b_row][jj]      + rhp[1][b_row][jj];
    const float rr2 = rhp[0][b_row][8 + jj]  + rhp[1][b_row][8 + jj];
    const float rg = rhp[0][b_row][16 + jj] + rhp[1][b_row][16 + jj];
    {
      float s = rz + rr2 + rg;
      float q = rz * rz + rr2 * rr2 + rg * rg;
      s += __shfl_xor(s, 1); q += __shfl_xor(q, 1);
      s += __shfl_xor(s, 2); q += __shfl_xor(q, 2);
      s += __shfl_xor(s, 4); q += __shfl_xor(q, 4);
      if (jj == 0) { statb[b_row][0] = s; statb[b_row][1] = q; }
    }
    __syncthreads();                                   // barrier 3

    // ---- tagged stats publish (wave0, 32 x 16B; no ack, no RMW, no poll)
    if (tid < 32) {
      f32x4 pv;
      pv[0] = statb[tid][0]; pv[1] = tagf;
      pv[2] = statb[tid][1]; pv[3] = tagf;
      stg_f32x4(pst + ((size_t)blk * 32 + tid) * 4, pv);
    }

    // ---- gather: 16 tagged quads in flight, validate, retry stale
    {
      f32x4 pv[16];
#pragma unroll
      for (int i = 0; i < 16; ++i) pv[i] = ldg_f32x4(gbase + i * 128);
      asm volatile("s_waitcnt vmcnt(0)" ::: "memory");
      float ss = 0.f, qq = 0.f;
#pragma unroll
      for (int i = 0; i < 16; ++i) {
        f32x4 v = pv[i];
        int spins = 0;
        while (v[1] != tagf || v[3] != tagf) {
          v = ldg_f32x4(gbase + i * 128);
          asm volatile("s_waitcnt vmcnt(0)" ::: "memory");
          if (++spins > (1 << 22)) break;   // bounded: wrong answer, not hang
        }
        ss += v[0]; qq += v[2];
      }
      predS[grp][rr] = ss; predQ[grp][rr] = qq;
    }
    __syncthreads();                                   // barrier 4
    float sfs = 0.f, sfq = 0.f;
#pragma unroll
    for (int g = 0; g < 8; ++g) {
      sfs += predS[g][b_row];
      sfq += predQ[g][b_row];
    }

    // ---- phase 2: finalize LN, gates, h update
    const float mean = sfs * (1.f / H3);
    const float var  = sfq * (1.f / H3) - mean * mean;
    const float inv  = __frsqrt_rn(var + LN_EPS);
    const float rzn = (rz - mean) * inv * grz;
    const float rrn = (rr2 - mean) * inv * grr;
    const float rgn = (rg - mean) * inv * grg;
    const float zg    = sigf(wz + bxz + rzn + brz);
    const float rgate = sigf(wr + bxr + rrn + brr);
    const float gg    = tanhfast(wg + bxg + rgate * (rgn + brg));
    const float hn = zg * hloc + (1.f - zg) * gg;
    hloc = hn;
    union { _Float16 f; unsigned short s; } hc; hc.f = (_Float16)hn;
    const unsigned short mybits = hc.s;
    const unsigned short pbits  = (unsigned short)__shfl_xor((int)mybits, 1);
    if ((jj & 1) == 0) {
      const unsigned w = (unsigned)mybits | ((unsigned)pbits << 16);
      ASTORE(&hglob[blk * 128 + b_row * 4 + (jj >> 1)], w);   // block-major publish
    }
    hs_out[(size_t)(b_row * TT + t) * HH + gi] = hc.f;        // L2-cached
    asm volatile("s_waitcnt vmcnt(0)" ::: "memory");          // wave-local drain
    if (lane == 0) AADD(&cntB[lineB]);                        // per-wave flag
  }
  hf32[b_row * HH + gi] = hloc;   // fp32 handoff to next layer (cached)
}

// ---------------------------------------------------------------------------
// out[16384][80] = tanh(hs @ Wlin + blin)
__global__ __launch_bounds__(256, 1) void k_proj(
    const _Float16* __restrict__ hs,
    const _Float16* __restrict__ Wlb,   // [80][1024] fp16
    const float* __restrict__ blin,
    float* __restrict__ out)
{
  const int tid = threadIdx.x, lane = tid & 63, wv = tid >> 6;
  const int l15 = lane & 15, quad = lane >> 4;
  const int mbase = blockIdx.x * 64 + wv * 16;
  f32x4 acc[5] = {{0.f,0.f,0.f,0.f},{0.f,0.f,0.f,0.f},{0.f,0.f,0.f,0.f},
                  {0.f,0.f,0.f,0.f},{0.f,0.f,0.f,0.f}};
  const _Float16* arow = hs + (size_t)(mbase + l15) * HH + quad * 8;
  for (int kc = 0; kc < HH; kc += 32) {
    const f16x8 af = *(const f16x8*)(arow + kc);
#pragma unroll
    for (int nt = 0; nt < 5; ++nt) {
      const f16x8 bv = *(const f16x8*)(Wlb + (size_t)(nt * 16 + l15) * HH + kc + quad * 8);
      acc[nt] = __builtin_amdgcn_mfma_f32_16x16x32_f16(af, bv, acc[nt], 0, 0, 0);
    }
  }
#pragma unroll
  for (int nt = 0; nt < 5; ++nt)
#pragma unroll
    for (int j = 0; j < 4; ++j) {
      const int col = nt * 16 + l15;
      out[(size_t)(mbase + quad * 4 + j) * 80 + col] = tanhf(acc[nt][j] + blin[col]);
    }
}

// ---------------------------------------------------------------------------
extern "C" void kernel_launch(void* const* d_in, const int* in_sizes, int n_in,
                              void* d_out, int out_size, void* d_ws, size_t ws_size,
                              hipStream_t stream)
{
  const float* x    = (const float*)d_in[0];
  const float* W0   = (const float*)d_in[1];
  const float* R0   = (const float*)d_in[2];
  const float* bx0  = (const float*)d_in[3];
  const float* br0  = (const float*)d_in[4];
  const float* gw0  = (const float*)d_in[5];
  const float* gr0  = (const float*)d_in[6];
  const float* Wk   = (const float*)d_in[7];
  const float* Rk   = (const float*)d_in[8];
  const float* bxk  = (const float*)d_in[9];
  const float* brk  = (const float*)d_in[10];
  const float* gwk  = (const float*)d_in[11];
  const float* grk  = (const float*)d_in[12];
  const float* Wlin = (const float*)d_in[13];
  const float* blin = (const float*)d_in[14];

  char* ws = (char*)d_ws;
  unsigned*  ctrl   = (unsigned*)(ws + OFF_CTRL);
  float*     pst    = (float*)(ws + OFF_PST);
  unsigned*  hglob  = (unsigned*)(ws + OFF_H);
  float*     hf32   = (float*)(ws + OFF_HF);
  _Float16*  Wlb    = (_Float16*)(ws + OFF_WLB);
  _Float16*  Wb     = (_Float16*)(ws + OFF_WB);
  _Float16*  xb     = (_Float16*)(ws + OFF_XBF);
  _Float16*  wx     = (_Float16*)(ws + OFF_WX);
  _Float16*  hsA    = (_Float16*)(ws + OFF_HSA);
  _Float16*  hsB    = (_Float16*)(ws + OFF_HSB);

  hipMemsetAsync(d_ws, 0, CTRL_BYTES, stream);   // cntB, tagged stats, h state

  k_init<<<2048, 256, 0, stream>>>(x, xb, Wlin, Wlb);

  for (int l = 0; l < 3; ++l) {
    const int K = l ? HH : 128;
    const float* Wl  = l ? (Wk  + (size_t)(l - 1) * HH * H3) : W0;
    const float* Rl  = l ? (Rk  + (size_t)(l - 1) * HH * H3) : R0;
    const float* bxl = l ? (bxk + (size_t)(l - 1) * H3) : bx0;
    const float* brl = l ? (brk + (size_t)(l - 1) * H3) : br0;
    const float* gwl = l ? (gwk + (size_t)(l - 1) * H3) : gw0;
    const float* grl = l ? (grk + (size_t)(l - 1) * H3) : gr0;
    const _Float16* Ain = (l == 0) ? xb : ((l == 1) ? hsA : hsB);
    _Float16* hs_out = (l == 1) ? hsB : hsA;

    k_convW<<<H3, 256, 0, stream>>>(Wl, Wb, K);
    k_gemm<<<12288, 256, 0, stream>>>(Ain, Wb, wx, K);
    k_ln<<<4096, 256, 0, stream>>>(wx, gwl);
    k_recur<<<NBLK_R, 256, 0, stream>>>(Rl, bxl, brl, grl, wx, hs_out,
                                        hglob, hf32, pst, ctrl,
                                        (unsigned)l * (unsigned)TT,
                                        (unsigned)l * (TT + 1u));
  }
  k_proj<<<256, 256, 0, stream>>>(hsA, Wlb, blin, (float*)d_out);
}

// Round 12
// 10596.655 us; speedup vs baseline: 1.5755x; 1.5755x over previous
//
#include <hip/hip_runtime.h>

// ---------------------------------------------------------------------------
// 3-layer LayerNorm-GRU (haste style), B=32 T=512 IN=128 H=1024 OUT=80
// Round 18: REVERT to R15 verbatim (best verified: 3357us/layer, 10.77ms).
//   R17 post-mortem: tagged data-as-flag gather retried 16 quads SERIALLY
//   (consumers arrive ~a barrier after their own publish, long before other
//   blocks' stores land) -> +2us/step. Third deviation from the barrier-
//   rendezvous protocol, third loss. The R15 structure stands:
//   - block-major hglob [128][32][4u32]: producer publish = 1 full 128B
//     line (sc1 write-through), consumer af loads bypass (sc0 sc1).
//   - 32-line sharded counters: cntB 16 adds/line (per-wave), cntA 4/line
//     (per-block); tid<32 tight polls + __syncthreads after every poll.
//   - LDS-staged stats: statb -> pstat publish -> flat allreduce (8
//     in-flight dwordx4/thread) -> pred tree -> broadcast finish.
//   - 5 barriers/step; sc1 publish -> wave vmcnt(0) -> counter add.
// ---------------------------------------------------------------------------

typedef float    f32x4 __attribute__((ext_vector_type(4)));
typedef _Float16 f16x8 __attribute__((ext_vector_type(8)));

#define HH      1024
#define TT      512
#define BBATCH  32
#define H3      3072
#define MROWS   16384      // B*T
#define NBLK_R  128        // compute blocks
#define HPB     8          // h-indices per recurrence block
#define COLS    24         // 3*HPB columns of R per block
#define LN_EPS  1e-5f

// workspace layout (bytes)
#define OFF_CTRL   0u                 // cntA 32 lines @0, cntB 32 lines @4096
#define OFF_PSTAT  8192u              // pstat[128][64] f32 = 32 KB (ends 40960)
#define OFF_H      40960u             // h fp16 block-major [128][32][8] = 64 KB
#define OFF_HF     106496u            // h fp32 [32][1024] = 128 KB (ends 237568)
#define CTRL_BYTES 237568u            // memset region
#define OFF_WLB    327680u            // Wlin^T fp16 [80][1024]  = 160 KB
#define OFF_WB     524288u            // W^T fp16 [3072][K<=1024] = 6 MB
#define OFF_XBF    (8ull<<20)         // x fp16 [16384][128]     = 4 MB
#define OFF_WX     (16ull<<20)        // wx fp16 [16384][3072]   = 96 MB
#define OFF_HSA    (112ull<<20)       // hs fp16 [16384][1024]   = 32 MB
#define OFF_HSB    (144ull<<20)       // hs fp16 [16384][1024]   = 32 MB  (end 176 MB)

#define ALOAD(p)    __hip_atomic_load((p),  __ATOMIC_RELAXED, __HIP_MEMORY_SCOPE_AGENT)
#define ASTORE(p,v) __hip_atomic_store((p), (v), __ATOMIC_RELAXED, __HIP_MEMORY_SCOPE_AGENT)
#define AADD(p)     __hip_atomic_fetch_add((p), 1u, __ATOMIC_RELAXED, __HIP_MEMORY_SCOPE_AGENT)

// LLC-coherent loads (bypass L1 via sc0, L2 via sc1); caller waits vmcnt
__device__ __forceinline__ f16x8 ldg_h16(const _Float16* p) {
  f16x8 r;
  asm volatile("global_load_dwordx4 %0, %1, off sc0 sc1" : "=v"(r) : "v"(p));
  return r;
}
__device__ __forceinline__ f32x4 ldg_f32x4(const float* p) {
  f32x4 r;
  asm volatile("global_load_dwordx4 %0, %1, off sc0 sc1" : "=v"(r) : "v"(p));
  return r;
}

__device__ __forceinline__ float sigf(float x) {
  return __builtin_amdgcn_rcpf(1.f + __expf(-x));
}
__device__ __forceinline__ float tanhfast(float x) {
  const float e2 = __expf(2.f * x);
  return 1.f - 2.f * __builtin_amdgcn_rcpf(e2 + 1.f);
}

// ---------------------------------------------------------------------------
// init: x fp32 -> fp16 ; Wlin [1024][80] -> Wlb^T fp16 [80][1024]
__global__ __launch_bounds__(256, 1) void k_init(
    const float* __restrict__ x, _Float16* __restrict__ xb,
    const float* __restrict__ Wlin, _Float16* __restrict__ Wlb)
{
  const size_t stride = (size_t)gridDim.x * 256;
  for (size_t i = (size_t)blockIdx.x * 256 + threadIdx.x; i < (size_t)MROWS * 128; i += stride)
    xb[i] = (_Float16)x[i];
  for (size_t i = (size_t)blockIdx.x * 256 + threadIdx.x; i < 80u * 1024u; i += stride) {
    const size_t n = i >> 10, k = i & 1023u;
    Wlb[i] = (_Float16)Wlin[k * 80 + n];
  }
}

// W fp32 [K][3072] -> Wb fp16 [3072][K] (n-major for B-fragments)
__global__ __launch_bounds__(256, 1) void k_convW(
    const float* __restrict__ W, _Float16* __restrict__ Wb, const int K)
{
  const int n = blockIdx.x;
  for (int k = threadIdx.x; k < K; k += 256)
    Wb[(size_t)n * K + k] = (_Float16)W[(size_t)k * H3 + n];
}

// Cw[16384][3072] (fp16, raw pre-LN) = A[16384][K] @ W[K][3072]
__global__ __launch_bounds__(256, 1) void k_gemm(
    const _Float16* __restrict__ A,
    const _Float16* __restrict__ Bw,   // [3072][K]
    _Float16* __restrict__ Cw,
    const int K)
{
  __shared__ _Float16 Bs[64][40];
  const int tid = threadIdx.x;
  const int lane = tid & 63, wv = tid >> 6;
  const int l15 = lane & 15, quad = lane >> 4;
  const int tilem = blockIdx.x / 48, tilen = blockIdx.x % 48;
  const int mbase = tilem * 64 + wv * 16;
  const size_t nbase = (size_t)tilen * 64;
  f32x4 acc[4] = {{0.f,0.f,0.f,0.f},{0.f,0.f,0.f,0.f},{0.f,0.f,0.f,0.f},{0.f,0.f,0.f,0.f}};
  const _Float16* arow = A + (size_t)(mbase + l15) * K + quad * 8;
  const int sn = tid >> 2, sk = (tid & 3) * 8;
  const _Float16* bsrc = Bw + (nbase + sn) * K + sk;
  for (int kc = 0; kc < K; kc += 32) {
    __syncthreads();
    *(f16x8*)(&Bs[sn][sk]) = *(const f16x8*)(bsrc + kc);
    __syncthreads();
    const f16x8 af = *(const f16x8*)(arow + kc);
#pragma unroll
    for (int nt = 0; nt < 4; ++nt) {
      const f16x8 bv = *(const f16x8*)(&Bs[nt * 16 + l15][quad * 8]);
      acc[nt] = __builtin_amdgcn_mfma_f32_16x16x32_f16(af, bv, acc[nt], 0, 0, 0);
    }
  }
#pragma unroll
  for (int nt = 0; nt < 4; ++nt)
#pragma unroll
    for (int j = 0; j < 4; ++j)
      Cw[(size_t)(mbase + quad * 4 + j) * H3 + nbase + nt * 16 + l15] = (_Float16)acc[nt][j];
}

// in-place LayerNorm * gw over rows of wx (3072 cols), one row per wave
__global__ __launch_bounds__(256, 1) void k_ln(
    _Float16* __restrict__ wxp, const float* __restrict__ gw)
{
  const int wv = threadIdx.x >> 6, lane = threadIdx.x & 63;
  const size_t row = (size_t)blockIdx.x * 4 + wv;
  _Float16* p = wxp + row * H3 + lane * 8;
  float vals[48];
  float s = 0.f, q = 0.f;
#pragma unroll
  for (int c = 0; c < 6; ++c) {
    const f16x8 v = *(const f16x8*)(p + c * 512);
#pragma unroll
    for (int j = 0; j < 8; ++j) {
      const float f = (float)v[j];
      vals[c * 8 + j] = f; s += f; q += f * f;
    }
  }
#pragma unroll
  for (int m = 1; m < 64; m <<= 1) { s += __shfl_xor(s, m); q += __shfl_xor(q, m); }
  const float mean = s * (1.f / H3);
  const float var  = q * (1.f / H3) - mean * mean;
  const float inv  = rsqrtf(var + LN_EPS);
#pragma unroll
  for (int c = 0; c < 6; ++c) {
    f16x8 o;
#pragma unroll
    for (int j = 0; j < 8; ++j)
      o[j] = (_Float16)((vals[c * 8 + j] - mean) * inv * gw[c * 512 + lane * 8 + j]);
    *(f16x8*)(p + c * 512) = o;
  }
}

// ---------------------------------------------------------------------------
// recurrence: 512 steps, 128 blocks, R15 protocol, 32-line counter shards
__global__ __launch_bounds__(256, 1) void k_recur(
    const float* __restrict__ R, const float* __restrict__ bx,
    const float* __restrict__ br, const float* __restrict__ gr,
    const _Float16* __restrict__ wx,
    _Float16* __restrict__ hs_out,
    unsigned* __restrict__ hglob,     // h fp16 block-major [128][32][8] as u32
    float* __restrict__ hf32,
    float* __restrict__ pstat,        // [128][64] partial stats
    unsigned* __restrict__ ctrl,
    const unsigned abase,             // l*TT
    const unsigned hbase)             // l*(TT+1)
{
  const int tid = threadIdx.x;
  const int blk = blockIdx.x;
  unsigned* cntA = ctrl;              // 32 lines, word stride 32 (4 adds/line)
  unsigned* cntB = ctrl + 1024;       // 32 lines, word stride 32 (16 adds/line)

  __shared__ _Float16 Rs[COLS][HH + 8];
  __shared__ float rhp[2][BBATCH][27];    // K-half partials (odd stride)
  __shared__ float statb[BBATCH][2];
  __shared__ float pred[16][68];          // pstat row-group partials

  const int lane = tid & 63;
  const int wv   = tid >> 6;
  const int mh   = wv >> 1;       // which 16 batch rows
  const int kh   = wv & 1;        // which K half (512)
  const int l15  = lane & 15;
  const int quad = lane >> 4;
  const int kb   = kh * 512;
  const int lineB = ((blk & 7) * 4 + wv) * 32;   // cntB shard for this wave

  // load R slice (cols {i, H+i, 2H+i} for i in [blk*8, blk*8+8)), fp32->fp16
  for (int n = 0; n < COLS; ++n) {
    const int gc = (n >> 3) * HH + blk * HPB + (n & 7);
    for (int k = tid; k < HH; k += 256)
      Rs[n][k] = (_Float16)R[(size_t)k * H3 + gc];
  }

  // per-thread gate ownership: (batch row, h-index)
  const int b_row = tid >> 3;
  const int jj    = tid & 7;
  const int gi    = blk * HPB + jj;
  const float bxz = bx[gi], bxr = bx[HH + gi], bxg = bx[2 * HH + gi];
  const float brz = br[gi], brr = br[HH + gi], brg = br[2 * HH + gi];
  const float grz = gr[gi], grr = gr[HH + gi], grg = gr[2 * HH + gi];
  float hloc = hf32[b_row * HH + gi];

  // initial coherent publish of own h slice (block-major, sc1 u32 pairs)
  {
    union { _Float16 f; unsigned short s; } hc; hc.f = (_Float16)hloc;
    const unsigned short mybits = hc.s;
    const unsigned short pbits  = (unsigned short)__shfl_xor((int)mybits, 1);
    if ((jj & 1) == 0) {
      const unsigned w = (unsigned)mybits | ((unsigned)pbits << 16);
      ASTORE(&hglob[blk * 128 + b_row * 4 + (jj >> 1)], w);
    }
  }
  asm volatile("s_waitcnt vmcnt(0)" ::: "memory");   // wave-local drain
  if (lane == 0) AADD(&cntB[lineB]);

  // consumer base: block-major chunk (kh*64 + quad), row (mh*16 + l15)
  const _Float16* hread = (const _Float16*)hglob;
  const _Float16* hrow  = hread + (size_t)(kh * 64 + quad) * 256
                                + (size_t)(mh * 16 + l15) * 8;
  const int n1 = 16 + (l15 & 7);          // ntile1 row (lanes >=8 read dup, masked)

  for (int t = 0; t < TT; ++t) {
    // prefetch phase-2 wx operands (t-only dependence; L2-resident)
    const _Float16* wrow = wx + (size_t)(b_row * TT + t) * H3;
    const float wz = (float)wrow[gi];
    const float wr = (float)wrow[HH + gi];
    const float wg = (float)wrow[2 * HH + gi];

    // ---- wait for all 512 wave h-publishes (32 sharded lines, tight poll)
    if (tid < 32) {
      const unsigned* p = cntB + tid * 32;
      const unsigned tgt = 16u * (hbase + (unsigned)t + 1u);
      int spins = 0;
      while (ALOAD(p) < tgt) { if (++spins > (1 << 24)) break; }
    }
    __syncthreads();                                   // barrier 1

    // ---- phase 1: 16 LLC-coherent A loads fully in flight, then MFMA
    f16x8 af[16];
#pragma unroll
    for (int ks = 0; ks < 16; ++ks)
      af[ks] = ldg_h16(hrow + ks * 1024);              // +4 blocks per ks
    asm volatile("s_waitcnt vmcnt(0)" ::: "memory");
    f32x4 acc0 = {0.f,0.f,0.f,0.f}, acc1 = {0.f,0.f,0.f,0.f};
#pragma unroll
    for (int ks = 0; ks < 16; ++ks) {
      const f16x8 b0 = *(const f16x8*)(&Rs[l15][kb + ks * 32 + quad * 8]);
      acc0 = __builtin_amdgcn_mfma_f32_16x16x32_f16(af[ks], b0, acc0, 0, 0, 0);
      const f16x8 b1 = *(const f16x8*)(&Rs[n1][kb + ks * 32 + quad * 8]);
      acc1 = __builtin_amdgcn_mfma_f32_16x16x32_f16(af[ks], b1, acc1, 0, 0, 0);
    }
    // write K-half partials (C layout: row=quad*4+j, col=l15)
#pragma unroll
    for (int j = 0; j < 4; ++j) {
      rhp[kh][mh * 16 + quad * 4 + j][l15] = acc0[j];
      if (l15 < 8) rhp[kh][mh * 16 + quad * 4 + j][16 + l15] = acc1[j];
    }
    __syncthreads();                                   // barrier 2

    // ---- combine K halves; per-row LN partial stats (8-thread shfl reduce)
    const float rz = rhp[0][b_row][jj]      + rhp[1][b_row][jj];
    const float rr = rhp[0][b_row][8 + jj]  + rhp[1][b_row][8 + jj];
    const float rg = rhp[0][b_row][16 + jj] + rhp[1][b_row][16 + jj];
    {
      float s = rz + rr + rg;
      float q = rz * rz + rr * rr + rg * rg;
      s += __shfl_xor(s, 1); q += __shfl_xor(q, 1);
      s += __shfl_xor(s, 2); q += __shfl_xor(q, 2);
      s += __shfl_xor(s, 4); q += __shfl_xor(q, 4);
      if (jj == 0) { statb[b_row][0] = s; statb[b_row][1] = q; }
    }
    __syncthreads();                                   // barrier 3
    // publish pstat (wave 0 only; wave-local drain orders add after data)
    if (tid < 64) ASTORE(&pstat[blk * 64 + tid], statb[tid >> 1][tid & 1]);
    asm volatile("s_waitcnt vmcnt(0)" ::: "memory");
    if (tid == 0) AADD(&cntA[(blk & 31) * 32]);

    // ---- wait for all 128 pstat publishes (32 sharded lines)
    if (tid < 32) {
      const unsigned* p = cntA + tid * 32;
      const unsigned tgt = 4u * (abase + (unsigned)t + 1u);
      int spins = 0;
      while (ALOAD(p) < tgt) { if (++spins > (1 << 24)) break; }
    }
    __syncthreads();                                   // barrier 4

    // ---- flat allreduce: 8 coalesced bypass dwordx4 loads, all in flight
    {
      const int prow0 = tid >> 4;          // 0..15
      const int pcol  = (tid & 15) * 4;    // 0..60
      f32x4 pv0 = ldg_f32x4(pstat + (size_t)(prow0      ) * 64 + pcol);
      f32x4 pv1 = ldg_f32x4(pstat + (size_t)(prow0 +  16) * 64 + pcol);
      f32x4 pv2 = ldg_f32x4(pstat + (size_t)(prow0 +  32) * 64 + pcol);
      f32x4 pv3 = ldg_f32x4(pstat + (size_t)(prow0 +  48) * 64 + pcol);
      f32x4 pv4 = ldg_f32x4(pstat + (size_t)(prow0 +  64) * 64 + pcol);
      f32x4 pv5 = ldg_f32x4(pstat + (size_t)(prow0 +  80) * 64 + pcol);
      f32x4 pv6 = ldg_f32x4(pstat + (size_t)(prow0 +  96) * 64 + pcol);
      f32x4 pv7 = ldg_f32x4(pstat + (size_t)(prow0 + 112) * 64 + pcol);
      asm volatile("s_waitcnt vmcnt(0)" ::: "memory");
      const f32x4 pa = ((pv0 + pv1) + (pv2 + pv3)) + ((pv4 + pv5) + (pv6 + pv7));
      *(f32x4*)(&pred[prow0][pcol]) = pa;
    }
    __syncthreads();                                   // barrier 5
    // broadcast-read finish: 16 group-partials for own row (same-addr bcast)
    float sfs = 0.f, sfq = 0.f;
#pragma unroll
    for (int g = 0; g < 16; ++g) {
      sfs += pred[g][2 * b_row];
      sfq += pred[g][2 * b_row + 1];
    }

    // ---- phase 2: finalize LN, gates, h update
    const float mean = sfs * (1.f / H3);
    const float var  = sfq * (1.f / H3) - mean * mean;
    const float inv  = __frsqrt_rn(var + LN_EPS);
    const float rzn = (rz - mean) * inv * grz;
    const float rrn = (rr - mean) * inv * grr;
    const float rgn = (rg - mean) * inv * grg;
    const float zg    = sigf(wz + bxz + rzn + brz);
    const float rgate = sigf(wr + bxr + rrn + brr);
    const float gg    = tanhfast(wg + bxg + rgate * (rgn + brg));
    const float hn = zg * hloc + (1.f - zg) * gg;
    hloc = hn;
    union { _Float16 f; unsigned short s; } hc; hc.f = (_Float16)hn;
    const unsigned short mybits = hc.s;
    const unsigned short pbits  = (unsigned short)__shfl_xor((int)mybits, 1);
    if ((jj & 1) == 0) {
      const unsigned w = (unsigned)mybits | ((unsigned)pbits << 16);
      ASTORE(&hglob[blk * 128 + b_row * 4 + (jj >> 1)], w);   // block-major publish
    }
    hs_out[(size_t)(b_row * TT + t) * HH + gi] = hc.f;        // L2-cached
    asm volatile("s_waitcnt vmcnt(0)" ::: "memory");          // wave-local drain
    if (lane == 0) AADD(&cntB[lineB]);                        // per-wave flag
  }
  hf32[b_row * HH + gi] = hloc;   // fp32 handoff to next layer (cached)
}

// ---------------------------------------------------------------------------
// out[16384][80] = tanh(hs @ Wlin + blin)
__global__ __launch_bounds__(256, 1) void k_proj(
    const _Float16* __restrict__ hs,
    const _Float16* __restrict__ Wlb,   // [80][1024] fp16
    const float* __restrict__ blin,
    float* __restrict__ out)
{
  const int tid = threadIdx.x, lane = tid & 63, wv = tid >> 6;
  const int l15 = lane & 15, quad = lane >> 4;
  const int mbase = blockIdx.x * 64 + wv * 16;
  f32x4 acc[5] = {{0.f,0.f,0.f,0.f},{0.f,0.f,0.f,0.f},{0.f,0.f,0.f,0.f},
                  {0.f,0.f,0.f,0.f},{0.f,0.f,0.f,0.f}};
  const _Float16* arow = hs + (size_t)(mbase + l15) * HH + quad * 8;
  for (int kc = 0; kc < HH; kc += 32) {
    const f16x8 af = *(const f16x8*)(arow + kc);
#pragma unroll
    for (int nt = 0; nt < 5; ++nt) {
      const f16x8 bv = *(const f16x8*)(Wlb + (size_t)(nt * 16 + l15) * HH + kc + quad * 8);
      acc[nt] = __builtin_amdgcn_mfma_f32_16x16x32_f16(af, bv, acc[nt], 0, 0, 0);
    }
  }
#pragma unroll
  for (int nt = 0; nt < 5; ++nt)
#pragma unroll
    for (int j = 0; j < 4; ++j) {
      const int col = nt * 16 + l15;
      out[(size_t)(mbase + quad * 4 + j) * 80 + col] = tanhf(acc[nt][j] + blin[col]);
    }
}

// ---------------------------------------------------------------------------
extern "C" void kernel_launch(void* const* d_in, const int* in_sizes, int n_in,
                              void* d_out, int out_size, void* d_ws, size_t ws_size,
                              hipStream_t stream)
{
  const float* x    = (const float*)d_in[0];
  const float* W0   = (const float*)d_in[1];
  const float* R0   = (const float*)d_in[2];
  const float* bx0  = (const float*)d_in[3];
  const float* br0  = (const float*)d_in[4];
  const float* gw0  = (const float*)d_in[5];
  const float* gr0  = (const float*)d_in[6];
  const float* Wk   = (const float*)d_in[7];
  const float* Rk   = (const float*)d_in[8];
  const float* bxk  = (const float*)d_in[9];
  const float* brk  = (const float*)d_in[10];
  const float* gwk  = (const float*)d_in[11];
  const float* grk  = (const float*)d_in[12];
  const float* Wlin = (const float*)d_in[13];
  const float* blin = (const float*)d_in[14];

  char* ws = (char*)d_ws;
  unsigned*  ctrl   = (unsigned*)(ws + OFF_CTRL);
  float*     pstat  = (float*)(ws + OFF_PSTAT);
  unsigned*  hglob  = (unsigned*)(ws + OFF_H);
  float*     hf32   = (float*)(ws + OFF_HF);
  _Float16*  Wlb    = (_Float16*)(ws + OFF_WLB);
  _Float16*  Wb     = (_Float16*)(ws + OFF_WB);
  _Float16*  xb     = (_Float16*)(ws + OFF_XBF);
  _Float16*  wx     = (_Float16*)(ws + OFF_WX);
  _Float16*  hsA    = (_Float16*)(ws + OFF_HSA);
  _Float16*  hsB    = (_Float16*)(ws + OFF_HSB);

  hipMemsetAsync(d_ws, 0, CTRL_BYTES, stream);   // counters, pstat, h state

  k_init<<<2048, 256, 0, stream>>>(x, xb, Wlin, Wlb);

  for (int l = 0; l < 3; ++l) {
    const int K = l ? HH : 128;
    const float* Wl  = l ? (Wk  + (size_t)(l - 1) * HH * H3) : W0;
    const float* Rl  = l ? (Rk  + (size_t)(l - 1) * HH * H3) : R0;
    const float* bxl = l ? (bxk + (size_t)(l - 1) * H3) : bx0;
    const float* brl = l ? (brk + (size_t)(l - 1) * H3) : br0;
    const float* gwl = l ? (gwk + (size_t)(l - 1) * H3) : gw0;
    const float* grl = l ? (grk + (size_t)(l - 1) * H3) : gr0;
    const _Float16* Ain = (l == 0) ? xb : ((l == 1) ? hsA : hsB);
    _Float16* hs_out = (l == 1) ? hsB : hsA;

    k_convW<<<H3, 256, 0, stream>>>(Wl, Wb, K);
    k_gemm<<<12288, 256, 0, stream>>>(Ain, Wb, wx, K);
    k_ln<<<4096, 256, 0, stream>>>(wx, gwl);
    k_recur<<<NBLK_R, 256, 0, stream>>>(Rl, bxl, brl, grl, wx, hs_out,
                                        hglob, hf32, pstat, ctrl,
                                        (unsigned)l * (unsigned)TT,
                                        (unsigned)l * (TT + 1u));
  }
  k_proj<<<256, 256, 0, stream>>>(hsA, Wlb, blin, (float*)d_out);
}